// Round 1
// 151.811 us; speedup vs baseline: 1.0037x; 1.0037x over previous
//
#include <hip/hip_runtime.h>
#include <hip/hip_bf16.h>

// CMOW word-matrix chain product — R9: 4-wave blocks (CHUNK=16), 2-level tree,
// direct B0-frag gather (no X0 LDS staging), SGPR indices via readfirstlane.
// sent:[1024,64] i32; table:[30001,784] f32; out:[1024,784] f32.
//
// X = cur^T chain, X_new = M^T @ X via mfma_f32_16x16x32_bf16 (32x32 padded,
// 2x2 tiles), fp32 ~ hi+lo bf16, 3 products/tile. A (=M^T) gathered from
// global straight into A-frag pattern; X round-trips LDS (B-conv, swizzled).
//
// R9 vs R8:
//  - WPB 8->4 (256-thread blocks), CHUNK 8->16. __launch_bounds__(256,5):
//    VGPR cap 102 -> up to 5 blocks/CU = 20 waves/CU (R8's (512,4) = 4
//    waves/EU = only 2 blocks/CU = 16 waves), and grid 1024 fits one
//    resident round instead of two.
//  - tree: 3 levels/3 barriers -> 2 levels/2 barriers (3 matmuls vs 7).
//  - X0 staging removed: X0=M0^T in B-conv is per-lane CONTIGUOUS in M0
//    (M0[n][8q+j]) -> 4x float4 direct gather + existing masks. Step 1 does
//    no LDS at all; saves a fence + 12 LDS ops + divergent staging branch.
//  - indices -> SGPRs via readfirstlane (guaranteed saddr gathers), chain
//    fully unrolled so sidx[] indexing is static.

#define MD    28
#define MD2   784
#define SEQL  64
#define CHUNK 16
#define WPB   4

typedef __attribute__((ext_vector_type(8))) short bf16x8;
typedef __attribute__((ext_vector_type(4))) float floatx4;

#define LDS_FENCE() asm volatile("s_waitcnt lgkmcnt(0)" ::: "memory")

__device__ __forceinline__ unsigned short f2bf(float x) {
    unsigned u = __float_as_uint(x);
    unsigned r = u + 0x7FFFu + ((u >> 16) & 1u);
    return (unsigned short)(r >> 16);
}
__device__ __forceinline__ float bf2f(unsigned short h) {
    return __uint_as_float(((unsigned)h) << 16);
}

// pack 2 fp32 -> dword of 2 bf16 (RNE) via v_cvt_pk_bf16_f32
__device__ __forceinline__ unsigned pk_bf16(float x, float y) {
    float2 f; f.x = x; f.y = y;
    __hip_bfloat162 h2 = __float22bfloat162_rn(f);
    union { __hip_bfloat162 h; unsigned u; } cv; cv.h = h2;
    return cv.u;
}

union U4F { uint4 u; bf16x8 v; };

// 8 fp32 -> hi/lo bf16x8, then AND packed words with masks:
// words 0,1 &= m01 ; words 2,3 &= m23  (applied to both hi and lo)
__device__ __forceinline__ void pack8m(const float* v, unsigned m01, unsigned m23,
                                       bf16x8* hi, bf16x8* lo) {
    U4F H, L;
    unsigned* ph = (unsigned*)&H.u;
    unsigned* pl = (unsigned*)&L.u;
    #pragma unroll
    for (int p = 0; p < 4; ++p) {
        float x = v[2*p], y = v[2*p+1];
        unsigned h = pk_bf16(x, y);
        float rx = x - __uint_as_float(h << 16);
        float ry = y - __uint_as_float(h & 0xffff0000u);
        pl[p] = pk_bf16(rx, ry);
        ph[p] = h;
    }
    H.u.x &= m01; H.u.y &= m01; H.u.z &= m23; H.u.w &= m23;
    L.u.x &= m01; L.u.y &= m01; L.u.z &= m23; L.u.w &= m23;
    *hi = H.v; *lo = L.v;
}

// X-plane address (shorts): slot n (0..31), k-octet g (0..3), h (0=hi,1=lo)
__device__ __forceinline__ int xaddr(int n, int g, int h) {
    return n * 64 + ((h ^ (n & 1)) << 5) + ((g ^ ((n >> 1) & 3)) << 3);
}

struct Acc { floatx4 t[2][2]; };

__device__ __forceinline__ void acc_zero(Acc& a) {
    #pragma unroll
    for (int mi = 0; mi < 2; ++mi)
        #pragma unroll
        for (int ni = 0; ni < 2; ++ni)
            a.t[mi][ni] = (floatx4){0.f, 0.f, 0.f, 0.f};
}

__device__ __forceinline__ floatx4 mfma16(bf16x8 a, bf16x8 b, floatx4 c) {
    return __builtin_amdgcn_mfma_f32_16x16x32_bf16(a, b, c, 0, 0, 0);
}

__device__ __forceinline__ void mm12(bf16x8 ah0, bf16x8 ah1, bf16x8 al0, bf16x8 al1,
                                     bf16x8 bh0, bf16x8 bh1, bf16x8 bl0, bf16x8 bl1,
                                     Acc& acc) {
    acc.t[0][0] = mfma16(ah0, bh0, acc.t[0][0]);
    acc.t[0][1] = mfma16(ah0, bh1, acc.t[0][1]);
    acc.t[1][0] = mfma16(ah1, bh0, acc.t[1][0]);
    acc.t[1][1] = mfma16(ah1, bh1, acc.t[1][1]);
    acc.t[0][0] = mfma16(ah0, bl0, acc.t[0][0]);
    acc.t[0][1] = mfma16(ah0, bl1, acc.t[0][1]);
    acc.t[1][0] = mfma16(ah1, bl0, acc.t[1][0]);
    acc.t[1][1] = mfma16(ah1, bl1, acc.t[1][1]);
    acc.t[0][0] = mfma16(al0, bh0, acc.t[0][0]);
    acc.t[0][1] = mfma16(al0, bh1, acc.t[0][1]);
    acc.t[1][0] = mfma16(al1, bh0, acc.t[1][0]);
    acc.t[1][1] = mfma16(al1, bh1, acc.t[1][1]);
}

// B-frags from X plane (4x ds_read_b128)
__device__ __forceinline__ void readB(const unsigned short* X, int n16, int q,
                                      bf16x8* bh0, bf16x8* bh1, bf16x8* bl0, bf16x8* bl1) {
    *bh0 = *(const bf16x8*)(X + xaddr(n16,      q, 0));
    *bl0 = *(const bf16x8*)(X + xaddr(n16,      q, 1));
    *bh1 = *(const bf16x8*)(X + xaddr(16 + n16, q, 0));
    *bl1 = *(const bf16x8*)(X + xaddr(16 + n16, q, 1));
}

// D (C-layout) -> X plane B-conv (8x ds_write_b64)
__device__ __forceinline__ void writeX(unsigned short* X, const Acc& acc,
                                       int n16, int q) {
    const int sub = (q & 1) * 4;
    #pragma unroll
    for (int mi = 0; mi < 2; ++mi) {
        const int g = 2 * mi + (q >> 1);
        #pragma unroll
        for (int ni = 0; ni < 2; ++ni) {
            floatx4 a = acc.t[mi][ni];
            const int n = ni * 16 + n16;
            unsigned h0 = pk_bf16(a[0], a[1]);
            unsigned h1 = pk_bf16(a[2], a[3]);
            float r0 = a[0] - __uint_as_float(h0 << 16);
            float r1 = a[1] - __uint_as_float(h0 & 0xffff0000u);
            float r2 = a[2] - __uint_as_float(h1 << 16);
            float r3 = a[3] - __uint_as_float(h1 & 0xffff0000u);
            unsigned l0 = pk_bf16(r0, r1);
            unsigned l1 = pk_bf16(r2, r3);
            uint2 uh; uh.x = h0; uh.y = h1;
            uint2 ul; ul.x = l0; ul.y = l1;
            *(uint2*)(X + xaddr(n, g, 0) + sub) = uh;
            *(uint2*)(X + xaddr(n, g, 1) + sub) = ul;
        }
    }
}

// D (C-layout) -> A-conv (plain m*32+n, hi | lo+1024) into a plane region
__device__ __forceinline__ void writeAconv(unsigned short* P, const Acc& acc,
                                           int n16, int q) {
    unsigned short* Sh = P;
    unsigned short* Sl = P + 1024;
    #pragma unroll
    for (int mi = 0; mi < 2; ++mi)
        #pragma unroll
        for (int ni = 0; ni < 2; ++ni) {
            floatx4 a = acc.t[mi][ni];
            #pragma unroll
            for (int r = 0; r < 4; ++r) {
                int m = mi * 16 + q * 4 + r;
                int n = ni * 16 + n16;
                int off = m * 32 + n;
                unsigned short hh = f2bf(a[r]);
                Sh[off] = hh;
                Sl[off] = f2bf(a[r] - bf2f(hh));
            }
        }
}

__device__ __forceinline__ void readAconv(const unsigned short* P, int n16, int q,
                                          bf16x8* ah0, bf16x8* ah1,
                                          bf16x8* al0, bf16x8* al1) {
    const unsigned short* Sh = P;
    const unsigned short* Sl = P + 1024;
    const int o0 = n16 * 32 + 8 * q;
    const int o1 = (16 + n16) * 32 + 8 * q;
    *ah0 = *(const bf16x8*)(Sh + o0);
    *ah1 = *(const bf16x8*)(Sh + o1);
    *al0 = *(const bf16x8*)(Sl + o0);
    *al1 = *(const bf16x8*)(Sl + o1);
}

__global__ __launch_bounds__(256, 5)
void cmow_mfma_kernel(const int* __restrict__ sent,
                      const float* __restrict__ table,
                      float* __restrict__ out)
{
    // 4 planes of 2048 shorts (one per wave) = 16 KB
    __shared__ __align__(16) unsigned short smem[WPB * 2048];

    const int tid  = threadIdx.x;
    const int lane = tid & 63;
    const int w    = tid >> 6;
    const int b    = blockIdx.x;

    unsigned short* Xw = smem + w * 2048;

    // ---- wave-uniform indices -> SGPRs (4x int4 load + readfirstlane)
    const int* sp = sent + b * SEQL + w * CHUNK;
    int sidx[CHUNK];
    {
        const int4* sp4 = (const int4*)sp;
        #pragma unroll
        for (int g = 0; g < CHUNK / 4; ++g) {
            int4 v = sp4[g];
            sidx[4 * g + 0] = __builtin_amdgcn_readfirstlane(v.x);
            sidx[4 * g + 1] = __builtin_amdgcn_readfirstlane(v.y);
            sidx[4 * g + 2] = __builtin_amdgcn_readfirstlane(v.z);
            sidx[4 * g + 3] = __builtin_amdgcn_readfirstlane(v.w);
        }
    }

    const int n16 = lane & 15;
    const int q   = lane >> 4;

    // ---- loop-invariant gather offsets (elements) and padding masks.
    // pa[j] = M[8q+j][n16]        (k=8q+j; invalid iff q==3 && j>=4)
    // pb[j] = M[8q+j][16+n16]     (also invalid iff n16>=12)
    // j=4..7 use a clamped base (row 0 garbage for q==3), zeroed post-pack.
    const int colB  = (n16 < 12) ? (16 + n16) : 0;
    const int offA0 = (8 * q) * MD + n16;
    const int offA4 = ((q == 3) ? 0 : (8 * q + 4) * MD) + n16;
    const int offB0 = (8 * q) * MD + colB;
    const int offB4 = ((q == 3) ? 0 : (8 * q + 4) * MD) + colB;
    const unsigned mA23 = (q == 3) ? 0u : ~0u;
    const unsigned mB01 = (n16 < 12) ? ~0u : 0u;
    const unsigned mB23 = (n16 < 12 && q != 3) ? ~0u : 0u;

    // ---- first A prefetch (saddr + hoisted voffset + imm)
    float pa[8], pb[8];
    {
        const float* bp = table + (size_t)sidx[1] * MD2;
        #pragma unroll
        for (int j = 0; j < 4; ++j) {
            pa[j]     = bp[offA0 + j * MD];
            pb[j]     = bp[offB0 + j * MD];
            pa[4 + j] = bp[offA4 + j * MD];
            pb[4 + j] = bp[offB4 + j * MD];
        }
    }

    // ---- direct B0-frag gather: X0[k][n] = M0[n][k] is per-lane CONTIGUOUS.
    // pv0[j] = M0[n16][8q+j]      (4x float4, clamped+masked at k>=28 / n>=28)
    // pv1[j] = M0[16+n16][8q+j]
    float pv0[8], pv1[8];
    {
        const float* b0p = table + (size_t)sidx[0] * MD2;
        const int o00 = n16 * MD + 8 * q;
        const int o04 = (q == 3) ? 0 : (o00 + 4);
        const int r1  = (n16 < 12) ? (16 + n16) : 0;
        const int o10 = r1 * MD + 8 * q;
        const int o14 = (q == 3) ? 0 : (o10 + 4);
        *(float4*)(pv0)     = *(const float4*)(b0p + o00);
        *(float4*)(pv0 + 4) = *(const float4*)(b0p + o04);
        *(float4*)(pv1)     = *(const float4*)(b0p + o10);
        *(float4*)(pv1 + 4) = *(const float4*)(b0p + o14);
    }

    // ---- step 1: X1 = M1^T @ M0^T, fully from global (no LDS, no fence)
    {
        bf16x8 ah0, ah1, al0, al1;
        pack8m(pa, ~0u,  mA23, &ah0, &al0);
        pack8m(pb, mB01, mB23, &ah1, &al1);

        {   // prefetch A2
            const float* bp = table + (size_t)sidx[2] * MD2;
            #pragma unroll
            for (int j = 0; j < 4; ++j) {
                pa[j]     = bp[offA0 + j * MD];
                pb[j]     = bp[offB0 + j * MD];
                pa[4 + j] = bp[offA4 + j * MD];
                pb[4 + j] = bp[offB4 + j * MD];
            }
        }

        bf16x8 bh0, bh1, bl0, bl1;
        pack8m(pv0, ~0u,  mA23, &bh0, &bl0);  // rows>=28 of X0 zeroed via pv1 masks
        pack8m(pv1, mB01, mB23, &bh1, &bl1);  // cols(n)>=28 zeroed here

        Acc acc; acc_zero(acc);
        mm12(ah0, ah1, al0, al1, bh0, bh1, bl0, bl1, acc);
        writeX(Xw, acc, n16, q);
    }

    // ---- steps 2..15: chained X = M_i^T @ X (wave-private plane)
    #pragma unroll
    for (int i = 2; i < CHUNK; ++i) {
        bf16x8 ah0, ah1, al0, al1;
        pack8m(pa, ~0u,  mA23, &ah0, &al0);
        pack8m(pb, mB01, mB23, &ah1, &al1);

        if (i + 1 < CHUNK) {
            const float* bp = table + (size_t)sidx[i + 1] * MD2;
            #pragma unroll
            for (int j = 0; j < 4; ++j) {
                pa[j]     = bp[offA0 + j * MD];
                pb[j]     = bp[offB0 + j * MD];
                pa[4 + j] = bp[offA4 + j * MD];
                pb[4 + j] = bp[offB4 + j * MD];
            }
        }

        LDS_FENCE();   // drain prev writeX — hidden behind pack8

        bf16x8 bh0, bh1, bl0, bl1;
        readB(Xw, n16, q, &bh0, &bh1, &bl0, &bl1);

        Acc acc; acc_zero(acc);
        mm12(ah0, ah1, al0, al1, bh0, bh1, bl0, bl1, acc);

        if (i < CHUNK - 1 || (w & 1) == 0)
            writeX(Xw, acc, n16, q);        // B-conv, own plane
        else
            writeAconv(Xw, acc, n16, q);    // odd waves: final partial A-conv
    }

    // ---- phase 2: 2-level tree (X_w = P_w^T; final = P0 P1 P2 P3)
    __syncthreads();

    if (w < 2) {
        // Y_w = X_{2w+1} @ X_{2w}
        bf16x8 ah0, ah1, al0, al1, bh0, bh1, bl0, bl1;
        readAconv(smem + (2 * w + 1) * 2048, n16, q, &ah0, &ah1, &al0, &al1);
        readB(smem + (2 * w) * 2048, n16, q, &bh0, &bh1, &bl0, &bl1);
        Acc acc; acc_zero(acc);
        mm12(ah0, ah1, al0, al1, bh0, bh1, bl0, bl1, acc);
        if (w == 0) writeX(smem, acc, n16, q);                 // Y0 -> plane0 (B-conv)
        else        writeAconv(smem + 3 * 2048, acc, n16, q);  // Y1 -> plane3 (A-conv)
    }
    __syncthreads();

    if (w == 0) {
        // final^T = Y1 @ Y0
        bf16x8 ah0, ah1, al0, al1, bh0, bh1, bl0, bl1;
        readAconv(smem + 3 * 2048, n16, q, &ah0, &ah1, &al0, &al1);
        readB(smem, n16, q, &bh0, &bh1, &bl0, &bl1);
        Acc acc; acc_zero(acc);
        mm12(ah0, ah1, al0, al1, bh0, bh1, bl0, bl1, acc);

        float* op = out + (size_t)b * MD2;
        #pragma unroll
        for (int mi = 0; mi < 2; ++mi)
            #pragma unroll
            for (int ni = 0; ni < 2; ++ni) {
                int C = ni * 16 + n16;       // cur row (= n of final^T)
                int R = mi * 16 + q * 4;     // cur col base (= m of final^T)
                if (C < MD && R + 3 < MD) {
                    floatx4 a = acc.t[mi][ni];
                    float4 st; st.x = a[0]; st.y = a[1]; st.z = a[2]; st.w = a[3];
                    *(float4*)(op + C * MD + R) = st;
                }
            }
    }
}

extern "C" void kernel_launch(void* const* d_in, const int* in_sizes, int n_in,
                              void* d_out, int out_size, void* d_ws, size_t ws_size,
                              hipStream_t stream) {
    const int*   sent  = (const int*)d_in[0];
    const float* table = (const float*)d_in[1];
    float*       outp  = (float*)d_out;

    const int batch = in_sizes[0] / SEQL;   // 1024
    cmow_mfma_kernel<<<dim3(batch), dim3(WPB * 64), 0, stream>>>(sent, table, outp);
}

// Round 3
// 150.387 us; speedup vs baseline: 1.0132x; 1.0095x over previous
//
#include <hip/hip_runtime.h>
#include <hip/hip_bf16.h>

// CMOW word-matrix chain product — R10 (resubmit; prior round hit an infra
// failure, kernel unmeasured): depth-2 rotating A-prefetch,
// __launch_bounds__(256,4) (VGPR cap 128). sent:[1024,64] i32;
// table:[30001,784] f32; out:[1024,784] f32.
//
// X = cur^T chain, X_new = M^T @ X via mfma_f32_16x16x32_bf16 (32x32 padded,
// 2x2 tiles), fp32 ~ hi+lo bf16, 3 products/tile. A (=M^T) gathered from
// global straight into A-frag pattern; X round-trips LDS (B-conv, swizzled).
//
// R10 vs R9:
//  - A-gather prefetch depth 1 -> 2: two matrices (32 dword loads) in flight;
//    consumption of step i's operands waits only past the step-(i+1) refill
//    (vmcnt(16)), covering the ~900cy cold-HBM gather latency (table is
//    evicted from L3 by the 376MB poison fills each iteration).
//  - chain macro-expanded: rotating buffers pa0/pb0, pa1/pb1 statically
//    indexed (no scratch).
//  - __launch_bounds__(256,4): VGPR cap 128 (R9's (256,5) capped at ~102,
//    tight for the extra prefetch regs). Still 4 blocks/CU, grid 1024 = one
//    resident round.

#define MD    28
#define MD2   784
#define SEQL  64
#define CHUNK 16
#define WPB   4

typedef __attribute__((ext_vector_type(8))) short bf16x8;
typedef __attribute__((ext_vector_type(4))) float floatx4;

#define LDS_FENCE() asm volatile("s_waitcnt lgkmcnt(0)" ::: "memory")

__device__ __forceinline__ unsigned short f2bf(float x) {
    unsigned u = __float_as_uint(x);
    unsigned r = u + 0x7FFFu + ((u >> 16) & 1u);
    return (unsigned short)(r >> 16);
}
__device__ __forceinline__ float bf2f(unsigned short h) {
    return __uint_as_float(((unsigned)h) << 16);
}

// pack 2 fp32 -> dword of 2 bf16 (RNE) via v_cvt_pk_bf16_f32
__device__ __forceinline__ unsigned pk_bf16(float x, float y) {
    float2 f; f.x = x; f.y = y;
    __hip_bfloat162 h2 = __float22bfloat162_rn(f);
    union { __hip_bfloat162 h; unsigned u; } cv; cv.h = h2;
    return cv.u;
}

union U4F { uint4 u; bf16x8 v; };

// 8 fp32 -> hi/lo bf16x8, then AND packed words with masks:
// words 0,1 &= m01 ; words 2,3 &= m23  (applied to both hi and lo)
__device__ __forceinline__ void pack8m(const float* v, unsigned m01, unsigned m23,
                                       bf16x8* hi, bf16x8* lo) {
    U4F H, L;
    unsigned* ph = (unsigned*)&H.u;
    unsigned* pl = (unsigned*)&L.u;
    #pragma unroll
    for (int p = 0; p < 4; ++p) {
        float x = v[2*p], y = v[2*p+1];
        unsigned h = pk_bf16(x, y);
        float rx = x - __uint_as_float(h << 16);
        float ry = y - __uint_as_float(h & 0xffff0000u);
        pl[p] = pk_bf16(rx, ry);
        ph[p] = h;
    }
    H.u.x &= m01; H.u.y &= m01; H.u.z &= m23; H.u.w &= m23;
    L.u.x &= m01; L.u.y &= m01; L.u.z &= m23; L.u.w &= m23;
    *hi = H.v; *lo = L.v;
}

// X-plane address (shorts): slot n (0..31), k-octet g (0..3), h (0=hi,1=lo)
__device__ __forceinline__ int xaddr(int n, int g, int h) {
    return n * 64 + ((h ^ (n & 1)) << 5) + ((g ^ ((n >> 1) & 3)) << 3);
}

struct Acc { floatx4 t[2][2]; };

__device__ __forceinline__ void acc_zero(Acc& a) {
    #pragma unroll
    for (int mi = 0; mi < 2; ++mi)
        #pragma unroll
        for (int ni = 0; ni < 2; ++ni)
            a.t[mi][ni] = (floatx4){0.f, 0.f, 0.f, 0.f};
}

__device__ __forceinline__ floatx4 mfma16(bf16x8 a, bf16x8 b, floatx4 c) {
    return __builtin_amdgcn_mfma_f32_16x16x32_bf16(a, b, c, 0, 0, 0);
}

__device__ __forceinline__ void mm12(bf16x8 ah0, bf16x8 ah1, bf16x8 al0, bf16x8 al1,
                                     bf16x8 bh0, bf16x8 bh1, bf16x8 bl0, bf16x8 bl1,
                                     Acc& acc) {
    acc.t[0][0] = mfma16(ah0, bh0, acc.t[0][0]);
    acc.t[0][1] = mfma16(ah0, bh1, acc.t[0][1]);
    acc.t[1][0] = mfma16(ah1, bh0, acc.t[1][0]);
    acc.t[1][1] = mfma16(ah1, bh1, acc.t[1][1]);
    acc.t[0][0] = mfma16(ah0, bl0, acc.t[0][0]);
    acc.t[0][1] = mfma16(ah0, bl1, acc.t[0][1]);
    acc.t[1][0] = mfma16(ah1, bl0, acc.t[1][0]);
    acc.t[1][1] = mfma16(ah1, bl1, acc.t[1][1]);
    acc.t[0][0] = mfma16(al0, bh0, acc.t[0][0]);
    acc.t[0][1] = mfma16(al0, bh1, acc.t[0][1]);
    acc.t[1][0] = mfma16(al1, bh0, acc.t[1][0]);
    acc.t[1][1] = mfma16(al1, bh1, acc.t[1][1]);
}

// B-frags from X plane (4x ds_read_b128)
__device__ __forceinline__ void readB(const unsigned short* X, int n16, int q,
                                      bf16x8* bh0, bf16x8* bh1, bf16x8* bl0, bf16x8* bl1) {
    *bh0 = *(const bf16x8*)(X + xaddr(n16,      q, 0));
    *bl0 = *(const bf16x8*)(X + xaddr(n16,      q, 1));
    *bh1 = *(const bf16x8*)(X + xaddr(16 + n16, q, 0));
    *bl1 = *(const bf16x8*)(X + xaddr(16 + n16, q, 1));
}

// D (C-layout) -> X plane B-conv (8x ds_write_b64)
__device__ __forceinline__ void writeX(unsigned short* X, const Acc& acc,
                                       int n16, int q) {
    const int sub = (q & 1) * 4;
    #pragma unroll
    for (int mi = 0; mi < 2; ++mi) {
        const int g = 2 * mi + (q >> 1);
        #pragma unroll
        for (int ni = 0; ni < 2; ++ni) {
            floatx4 a = acc.t[mi][ni];
            const int n = ni * 16 + n16;
            unsigned h0 = pk_bf16(a[0], a[1]);
            unsigned h1 = pk_bf16(a[2], a[3]);
            float r0 = a[0] - __uint_as_float(h0 << 16);
            float r1 = a[1] - __uint_as_float(h0 & 0xffff0000u);
            float r2 = a[2] - __uint_as_float(h1 << 16);
            float r3 = a[3] - __uint_as_float(h1 & 0xffff0000u);
            unsigned l0 = pk_bf16(r0, r1);
            unsigned l1 = pk_bf16(r2, r3);
            uint2 uh; uh.x = h0; uh.y = h1;
            uint2 ul; ul.x = l0; ul.y = l1;
            *(uint2*)(X + xaddr(n, g, 0) + sub) = uh;
            *(uint2*)(X + xaddr(n, g, 1) + sub) = ul;
        }
    }
}

// D (C-layout) -> A-conv (plain m*32+n, hi | lo+1024) into a plane region
__device__ __forceinline__ void writeAconv(unsigned short* P, const Acc& acc,
                                           int n16, int q) {
    unsigned short* Sh = P;
    unsigned short* Sl = P + 1024;
    #pragma unroll
    for (int mi = 0; mi < 2; ++mi)
        #pragma unroll
        for (int ni = 0; ni < 2; ++ni) {
            floatx4 a = acc.t[mi][ni];
            #pragma unroll
            for (int r = 0; r < 4; ++r) {
                int m = mi * 16 + q * 4 + r;
                int n = ni * 16 + n16;
                int off = m * 32 + n;
                unsigned short hh = f2bf(a[r]);
                Sh[off] = hh;
                Sl[off] = f2bf(a[r] - bf2f(hh));
            }
        }
}

__device__ __forceinline__ void readAconv(const unsigned short* P, int n16, int q,
                                          bf16x8* ah0, bf16x8* ah1,
                                          bf16x8* al0, bf16x8* al1) {
    const unsigned short* Sh = P;
    const unsigned short* Sl = P + 1024;
    const int o0 = n16 * 32 + 8 * q;
    const int o1 = (16 + n16) * 32 + 8 * q;
    *ah0 = *(const bf16x8*)(Sh + o0);
    *ah1 = *(const bf16x8*)(Sh + o1);
    *al0 = *(const bf16x8*)(Sl + o0);
    *al1 = *(const bf16x8*)(Sl + o1);
}

// gather one matrix's A/B operand slices into prefetch regs (16 dwords/lane)
#define GATHER(PA, PB, IDXV) do {                                   \
    const float* bp_ = table + (size_t)(IDXV) * MD2;                \
    _Pragma("unroll")                                               \
    for (int j_ = 0; j_ < 4; ++j_) {                                \
        (PA)[j_]     = bp_[offA0 + j_ * MD];                        \
        (PB)[j_]     = bp_[offB0 + j_ * MD];                        \
        (PA)[4 + j_] = bp_[offA4 + j_ * MD];                        \
        (PB)[4 + j_] = bp_[offB4 + j_ * MD];                        \
    }                                                               \
} while (0)

// one chain step: pack A from (PA,PB), refill that buffer for step I+2,
// fence, read B from LDS, 12 MFMA, write result back (B-conv or A-conv).
#define CHAINSTEP(I, PA, PB) do {                                   \
    bf16x8 ah0_, ah1_, al0_, al1_;                                  \
    pack8m(PA, ~0u,  mA23, &ah0_, &al0_);                           \
    pack8m(PB, mB01, mB23, &ah1_, &al1_);                           \
    if ((I) + 2 < CHUNK) GATHER(PA, PB, sidx[(I) + 2]);             \
    LDS_FENCE();                                                    \
    bf16x8 bh0_, bh1_, bl0_, bl1_;                                  \
    readB(Xw, n16, q, &bh0_, &bh1_, &bl0_, &bl1_);                  \
    Acc acc_; acc_zero(acc_);                                       \
    mm12(ah0_, ah1_, al0_, al1_, bh0_, bh1_, bl0_, bl1_, acc_);     \
    if ((I) < CHUNK - 1 || (w & 1) == 0)                            \
        writeX(Xw, acc_, n16, q);                                   \
    else                                                            \
        writeAconv(Xw, acc_, n16, q);                               \
} while (0)

__global__ __launch_bounds__(256, 4)
void cmow_mfma_kernel(const int* __restrict__ sent,
                      const float* __restrict__ table,
                      float* __restrict__ out)
{
    // 4 planes of 2048 shorts (one per wave) = 16 KB
    __shared__ __align__(16) unsigned short smem[WPB * 2048];

    const int tid  = threadIdx.x;
    const int lane = tid & 63;
    const int w    = tid >> 6;
    const int b    = blockIdx.x;

    unsigned short* Xw = smem + w * 2048;

    // ---- wave-uniform indices -> SGPRs (4x int4 load + readfirstlane)
    const int* sp = sent + b * SEQL + w * CHUNK;
    int sidx[CHUNK];
    {
        const int4* sp4 = (const int4*)sp;
        #pragma unroll
        for (int g = 0; g < CHUNK / 4; ++g) {
            int4 v = sp4[g];
            sidx[4 * g + 0] = __builtin_amdgcn_readfirstlane(v.x);
            sidx[4 * g + 1] = __builtin_amdgcn_readfirstlane(v.y);
            sidx[4 * g + 2] = __builtin_amdgcn_readfirstlane(v.z);
            sidx[4 * g + 3] = __builtin_amdgcn_readfirstlane(v.w);
        }
    }

    const int n16 = lane & 15;
    const int q   = lane >> 4;

    // ---- loop-invariant gather offsets (elements) and padding masks.
    // pa[j] = M[8q+j][n16]        (k=8q+j; invalid iff q==3 && j>=4)
    // pb[j] = M[8q+j][16+n16]     (also invalid iff n16>=12)
    // j=4..7 use a clamped base (row 0 garbage for q==3), zeroed post-pack.
    const int colB  = (n16 < 12) ? (16 + n16) : 0;
    const int offA0 = (8 * q) * MD + n16;
    const int offA4 = ((q == 3) ? 0 : (8 * q + 4) * MD) + n16;
    const int offB0 = (8 * q) * MD + colB;
    const int offB4 = ((q == 3) ? 0 : (8 * q + 4) * MD) + colB;
    const unsigned mA23 = (q == 3) ? 0u : ~0u;
    const unsigned mB01 = (n16 < 12) ? ~0u : 0u;
    const unsigned mB23 = (n16 < 12 && q != 3) ? ~0u : 0u;

    // ---- depth-2 rotating prefetch: buf0 <- A1, buf1 <- A2
    float pa0[8], pb0[8], pa1[8], pb1[8];
    GATHER(pa0, pb0, sidx[1]);
    GATHER(pa1, pb1, sidx[2]);

    // ---- direct B0-frag gather: X0[k][n] = M0[n][k] is per-lane CONTIGUOUS.
    // pv0[j] = M0[n16][8q+j]      (4x float4, clamped+masked at k>=28 / n>=28)
    // pv1[j] = M0[16+n16][8q+j]
    float pv0[8], pv1[8];
    {
        const float* b0p = table + (size_t)sidx[0] * MD2;
        const int o00 = n16 * MD + 8 * q;
        const int o04 = (q == 3) ? 0 : (o00 + 4);
        const int r1  = (n16 < 12) ? (16 + n16) : 0;
        const int o10 = r1 * MD + 8 * q;
        const int o14 = (q == 3) ? 0 : (o10 + 4);
        *(float4*)(pv0)     = *(const float4*)(b0p + o00);
        *(float4*)(pv0 + 4) = *(const float4*)(b0p + o04);
        *(float4*)(pv1)     = *(const float4*)(b0p + o10);
        *(float4*)(pv1 + 4) = *(const float4*)(b0p + o14);
    }

    // ---- step 1: X1 = M1^T @ M0^T, fully from global (no LDS, no fence)
    {
        bf16x8 ah0, ah1, al0, al1;
        pack8m(pa0, ~0u,  mA23, &ah0, &al0);
        pack8m(pb0, mB01, mB23, &ah1, &al1);

        GATHER(pa0, pb0, sidx[3]);   // refill buf0 for step 3

        bf16x8 bh0, bh1, bl0, bl1;
        pack8m(pv0, ~0u,  mA23, &bh0, &bl0);  // rows>=28 of X0 zeroed
        pack8m(pv1, mB01, mB23, &bh1, &bl1);  // cols(n)>=28 zeroed

        Acc acc; acc_zero(acc);
        mm12(ah0, ah1, al0, al1, bh0, bh1, bl0, bl1, acc);
        writeX(Xw, acc, n16, q);
    }

    // ---- steps 2..15: chained X = M_i^T @ X (wave-private plane).
    // step i consumes buf (i+1)&1 and refills it for step i+2.
    CHAINSTEP( 2, pa1, pb1);
    CHAINSTEP( 3, pa0, pb0);
    CHAINSTEP( 4, pa1, pb1);
    CHAINSTEP( 5, pa0, pb0);
    CHAINSTEP( 6, pa1, pb1);
    CHAINSTEP( 7, pa0, pb0);
    CHAINSTEP( 8, pa1, pb1);
    CHAINSTEP( 9, pa0, pb0);
    CHAINSTEP(10, pa1, pb1);
    CHAINSTEP(11, pa0, pb0);
    CHAINSTEP(12, pa1, pb1);
    CHAINSTEP(13, pa0, pb0);
    CHAINSTEP(14, pa1, pb1);
    CHAINSTEP(15, pa0, pb0);

    // ---- phase 2: 2-level tree (X_w = P_w^T; final = P0 P1 P2 P3)
    __syncthreads();

    if (w < 2) {
        // Y_w = X_{2w+1} @ X_{2w}
        bf16x8 ah0, ah1, al0, al1, bh0, bh1, bl0, bl1;
        readAconv(smem + (2 * w + 1) * 2048, n16, q, &ah0, &ah1, &al0, &al1);
        readB(smem + (2 * w) * 2048, n16, q, &bh0, &bh1, &bl0, &bl1);
        Acc acc; acc_zero(acc);
        mm12(ah0, ah1, al0, al1, bh0, bh1, bl0, bl1, acc);
        if (w == 0) writeX(smem, acc, n16, q);                 // Y0 -> plane0 (B-conv)
        else        writeAconv(smem + 3 * 2048, acc, n16, q);  // Y1 -> plane3 (A-conv)
    }
    __syncthreads();

    if (w == 0) {
        // final^T = Y1 @ Y0
        bf16x8 ah0, ah1, al0, al1, bh0, bh1, bl0, bl1;
        readAconv(smem + 3 * 2048, n16, q, &ah0, &ah1, &al0, &al1);
        readB(smem, n16, q, &bh0, &bh1, &bl0, &bl1);
        Acc acc; acc_zero(acc);
        mm12(ah0, ah1, al0, al1, bh0, bh1, bl0, bl1, acc);

        float* op = out + (size_t)b * MD2;
        #pragma unroll
        for (int mi = 0; mi < 2; ++mi)
            #pragma unroll
            for (int ni = 0; ni < 2; ++ni) {
                int C = ni * 16 + n16;       // cur row (= n of final^T)
                int R = mi * 16 + q * 4;     // cur col base (= m of final^T)
                if (C < MD && R + 3 < MD) {
                    floatx4 a = acc.t[mi][ni];
                    float4 st; st.x = a[0]; st.y = a[1]; st.z = a[2]; st.w = a[3];
                    *(float4*)(op + C * MD + R) = st;
                }
            }
    }
}

extern "C" void kernel_launch(void* const* d_in, const int* in_sizes, int n_in,
                              void* d_out, int out_size, void* d_ws, size_t ws_size,
                              hipStream_t stream) {
    const int*   sent  = (const int*)d_in[0];
    const float* table = (const float*)d_in[1];
    float*       outp  = (float*)d_out;

    const int batch = in_sizes[0] / SEQL;   // 1024
    cmow_mfma_kernel<<<dim3(batch), dim3(WPB * 64), 0, stream>>>(sent, table, outp);
}